// Round 2
// baseline (1933.007 us; speedup 1.0000x reference)
//
#include <hip/hip_runtime.h>
#include <hip/hip_bf16.h>

#define NN 50000
#define NE 800000
#define NEP (NE + NN)   // edges incl. self-loops
#define IND 128
#define NH 8

typedef __hip_bfloat16 bf16;

// External float input: dtype decided at runtime by detect_kernel (f==1 -> fp32, f==0 -> bf16)
static __device__ __forceinline__ float ldext(const void* p, long i, int f) {
    return f ? ((const float*)p)[i] : __bfloat162float(((const bf16*)p)[i]);
}
// Order-preserving float<->uint encoding for atomicMax on floats
static __device__ __forceinline__ unsigned encf(float x) {
    unsigned u = __float_as_uint(x);
    return (u & 0x80000000u) ? ~u : (u | 0x80000000u);
}
static __device__ __forceinline__ float decf(unsigned u) {
    return __uint_as_float((u & 0x80000000u) ? (u & 0x7FFFFFFFu) : ~u);
}

// ---------------- dtype detector ----------------
// If x is bf16-packed, the low 16 bits of each uint32 word are a genuine N(0,1) bf16
// (exponent in a narrow band). If x is fp32, the low 16 bits are mantissa noise.
__global__ void detect_kernel(const unsigned* __restrict__ x, int* __restrict__ flag) {
    __shared__ int sh[256];
    int tid = threadIdx.x, cnt = 0;
    for (int i = tid; i < 4096; i += 256) {
        unsigned lo = x[i] & 0xffffu;
        int e = (int)((lo >> 7) & 0xff);
        if ((e >= 0x60 && e <= 0x86) || (lo & 0x7fffu) == 0) cnt++;
    }
    sh[tid] = cnt; __syncthreads();
    for (int st = 128; st; st >>= 1) { if (tid < st) sh[tid] += sh[tid + st]; __syncthreads(); }
    if (tid == 0) *flag = (sh[0] < 2048) ? 1 : 0;
}

// ---------------- utility kernels ----------------
__global__ void zero_kernel(float* p, int n) {
    int i = blockIdx.x * 256 + threadIdx.x;
    if (i < n) p[i] = 0.f;
}
__global__ void init_deg_kernel(float* deg, int n) {
    int i = blockIdx.x * 256 + threadIdx.x;
    if (i < n) deg[i] = 1.f;   // self-loop
}
__global__ void count_deg_kernel(const int* __restrict__ edst, float* deg, int e) {
    int i = blockIdx.x * 256 + threadIdx.x;
    if (i < e) atomicAdd(&deg[edst[i]], 1.f);
}
__global__ void rsqrt_kernel(float* deg, int n) {
    int i = blockIdx.x * 256 + threadIdx.x;
    if (i < n) deg[i] = rsqrtf(deg[i]);
}
__global__ void init_mx_dn_kernel(unsigned* mx, float* dn, int n) {
    int i = blockIdx.x * 256 + threadIdx.x;
    if (i < n) { mx[i] = encf(-1e30f); dn[i] = 0.f; }
}

// ---------------- matmul: C[n,M] = A[n,K] @ W[K,M] ----------------
template<int K, bool AINT, bool CBF16>
__global__ __launch_bounds__(256) void mm_kernel(const void* __restrict__ A,
        const void* __restrict__ W, void* __restrict__ C,
        int nrows, int M, const int* __restrict__ dtf) {
    __shared__ float Alds[16][K];
    __shared__ float Wlds[K][64];
    const int f = *dtf;
    const int row0 = blockIdx.x * 16;
    const int m0   = blockIdx.y * 64;
    const int tid  = threadIdx.x;
    for (int idx = tid; idx < K * 64; idx += 256) {
        int k = idx >> 6, m = idx & 63;
        Wlds[k][m] = ldext(W, (long)k * M + m0 + m, f);
    }
    for (int idx = tid; idx < 16 * K; idx += 256) {
        int r = idx / K, k = idx % K;
        int row = row0 + r;
        float v = 0.f;
        if (row < nrows)
            v = AINT ? ((const float*)A)[(long)row * K + k] : ldext(A, (long)row * K + k, f);
        Alds[r][k] = v;
    }
    __syncthreads();
    const int m = tid & 63, rg = tid >> 6;
    float acc[4] = {0.f, 0.f, 0.f, 0.f};
    for (int k = 0; k < K; ++k) {
        float w = Wlds[k][m];
#pragma unroll
        for (int j = 0; j < 4; ++j) acc[j] += Alds[rg * 4 + j][k] * w;
    }
#pragma unroll
    for (int j = 0; j < 4; ++j) {
        int row = row0 + rg * 4 + j;
        if (row < nrows) {
            long o = (long)row * M + m0 + m;
            if (CBF16) ((bf16*)C)[o] = __float2bfloat16(acc[j]);
            else       ((float*)C)[o] = acc[j];
        }
    }
}

// ---------------- GCN ----------------
__global__ void self_init_kernel(const float* __restrict__ dinv,
        const float* __restrict__ hin, float* __restrict__ hout, int n) {
    int idx = blockIdx.x * 256 + threadIdx.x;
    if (idx >= n * 64) return;
    float di = dinv[idx >> 6];
    hout[idx] = di * di * hin[idx];
}
__global__ void gcn_edge_kernel(const int* __restrict__ esrc, const int* __restrict__ edst,
        const float* __restrict__ dinv, const float* __restrict__ hin,
        float* __restrict__ hout, int e) {
    int idx = blockIdx.x * 256 + threadIdx.x;
    if (idx >= e * 64) return;
    int eid = idx >> 6, c = idx & 63;
    int s = esrc[eid], d = edst[eid];
    float coef = dinv[s] * dinv[d];
    atomicAdd(&hout[(long)d * 64 + c], coef * hin[(long)s * 64 + c]);
}
__global__ void bias_bn_relu_kernel(float* __restrict__ h, const void* b,
        const void* gamma, const void* beta, const void* mean, const void* var,
        int n, const int* __restrict__ dtf) {
    int idx = blockIdx.x * 256 + threadIdx.x;
    if (idx >= n * 64) return;
    int f = *dtf;
    int c = idx & 63;
    float x = h[idx] + ldext(b, c, f);
    x = (x - ldext(mean, c, f)) * rsqrtf(ldext(var, c, f) + 1e-5f)
        * ldext(gamma, c, f) + ldext(beta, c, f);
    h[idx] = fmaxf(x, 0.f);
}

// ---------------- GAT ----------------
template<int C>
__global__ void att_scores_kernel(const bf16* __restrict__ ht,
        const void* asrc, const void* adst,
        float* __restrict__ es, float* __restrict__ ed, int n, const int* __restrict__ dtf) {
    int idx = blockIdx.x * 256 + threadIdx.x;
    if (idx >= n * NH) return;
    int f = *dtf;
    int nd = idx >> 3, h = idx & 7;
    const bf16* hp = ht + (long)nd * NH * C + h * C;
    float s = 0.f, d = 0.f;
    for (int c = 0; c < C; ++c) {
        float v = __bfloat162float(hp[c]);
        s += v * ldext(asrc, h * C + c, f);
        d += v * ldext(adst, h * C + c, f);
    }
    es[idx] = s; ed[idx] = d;
}
__global__ void att_edge_max_kernel(const int* __restrict__ esrc, const int* __restrict__ edst,
        const float* __restrict__ es, const float* __restrict__ ed,
        float* __restrict__ elog, unsigned* __restrict__ mx, int e, int ep) {
    int idx = blockIdx.x * 256 + threadIdx.x;
    if (idx >= ep * NH) return;
    int eid = idx >> 3, h = idx & 7;
    int s, d;
    if (eid < e) { s = esrc[eid]; d = edst[eid]; } else { s = d = eid - e; }
    float v = es[s * NH + h] + ed[d * NH + h];
    v = v > 0.f ? v : 0.2f * v;   // leaky_relu 0.2
    elog[idx] = v;
    atomicMax(&mx[d * NH + h], encf(v));
}
__global__ void att_exp_sum_kernel(const int* __restrict__ edst,
        const unsigned* __restrict__ mx, float* __restrict__ dn,
        float* __restrict__ elog, int e, int ep) {
    int idx = blockIdx.x * 256 + threadIdx.x;
    if (idx >= ep * NH) return;
    int eid = idx >> 3, h = idx & 7;
    int d = (eid < e) ? edst[eid] : eid - e;
    float m = decf(mx[d * NH + h]);
    float ex = expf(fminf(elog[idx] - m, 0.f));
    elog[idx] = ex;
    atomicAdd(&dn[d * NH + h], ex);
}
template<int C>
__global__ __launch_bounds__(256) void att_message_kernel(const int* __restrict__ esrc,
        const int* __restrict__ edst, const float* __restrict__ ex,
        const float* __restrict__ dn, const bf16* __restrict__ ht,
        float* __restrict__ out, int e, int ep) {
    constexpr int EPB = 256 / C;
    __shared__ float alpha[EPB][NH];
    __shared__ int ssrc[EPB], sdst[EPB];
    const int e0 = blockIdx.x * EPB;
    const int tid = threadIdx.x;
    if (tid < EPB * NH) {
        int le = tid >> 3, h = tid & 7;
        int eid = e0 + le;
        if (eid < ep) {
            int s, d;
            if (eid < e) { s = esrc[eid]; d = edst[eid]; } else { s = d = eid - e; }
            if (h == 0) { ssrc[le] = s; sdst[le] = d; }
            alpha[le][h] = ex[(long)eid * NH + h] / (dn[d * NH + h] + 1e-16f);
        }
    }
    __syncthreads();
    int le = tid / C, c = tid % C;
    int eid = e0 + le;
    if (eid >= ep) return;
    int s = ssrc[le], d = sdst[le];
    const bf16* hp = ht + (long)s * NH * C + c;
    float acc = 0.f;
#pragma unroll
    for (int h = 0; h < NH; ++h) acc += alpha[le][h] * __bfloat162float(hp[h * C]);
    atomicAdd(&out[(long)d * C + c], acc);
}
__global__ void gat_bias_relu_kernel(float* __restrict__ h, const void* b, int n,
                                     const int* __restrict__ dtf) {
    int idx = blockIdx.x * 256 + threadIdx.x;
    if (idx >= n * 64) return;
    float v = h[idx] * 0.125f + ldext(b, idx & 63, *dtf);
    h[idx] = fmaxf(v, 0.f);
}
__global__ __launch_bounds__(256) void logsoftmax_kernel(const float* __restrict__ acc,
        const void* b, void* out, int n, const int* __restrict__ dtf) {
    int idx = blockIdx.x * 256 + threadIdx.x;
    int nd = idx >> 5, lane = idx & 31;
    if (nd >= n) return;
    int f = *dtf;
    float v = acc[idx] * 0.125f + ldext(b, lane, f);
    float m = v;
    for (int off = 16; off; off >>= 1) m = fmaxf(m, __shfl_xor(m, off, 32));
    float exv = expf(v - m);
    float ssum = exv;
    for (int off = 16; off; off >>= 1) ssum += __shfl_xor(ssum, off, 32);
    float r = v - m - logf(ssum);
    if (f) ((float*)out)[idx] = r;
    else   ((bf16*)out)[idx] = __float2bfloat16(r);
}

// ---------------- launch ----------------
extern "C" void kernel_launch(void* const* d_in, const int* in_sizes, int n_in,
                              void* d_out, int out_size, void* d_ws, size_t ws_size,
                              hipStream_t stream) {
    const void* x        = d_in[0];
    const int*  eidx     = (const int*)d_in[1];
    const void* gcn1_w   = d_in[2];
    const void* gcn1_b   = d_in[3];
    const void* bn1_g    = d_in[4];
    const void* bn1_b    = d_in[5];
    const void* bn1_m    = d_in[6];
    const void* bn1_v    = d_in[7];
    const void* gat1_w   = d_in[8];
    const void* gat1_as  = d_in[9];
    const void* gat1_ad  = d_in[10];
    const void* gat1_b   = d_in[11];
    const void* gcn2_w   = d_in[12];
    const void* gcn2_b   = d_in[13];
    const void* bn2_g    = d_in[14];
    const void* bn2_b    = d_in[15];
    const void* bn2_m    = d_in[16];
    const void* bn2_v    = d_in[17];
    const void* gat2_w   = d_in[18];
    const void* gat2_as  = d_in[19];
    const void* gat2_ad  = d_in[20];
    const void* gat2_b   = d_in[21];

    const int* esrc = eidx;
    const int* edst = eidx + NE;

    float* ws = (float*)d_ws;
    int*      flag = (int*)ws;                              // ws[0]
    float*    dinv = ws + 64;
    float*    bufA = dinv + 50048;                          // N*64
    float*    bufB = bufA + (size_t)NN * 64;                // N*64
    float*    es   = bufB + (size_t)NN * 64;                // N*8
    float*    ed   = es + (size_t)NN * NH;                  // N*8
    unsigned* mx   = (unsigned*)(ed + (size_t)NN * NH);     // N*8
    float*    dn   = ed + (size_t)NN * NH * 2;              // N*8
    float*    elog = dn + (size_t)NN * NH;                  // NEP*8
    bf16*     htb  = (bf16*)(elog + (size_t)NEP * NH);      // N*512 bf16
    // total ~110.6 MB

    auto cdiv = [](long a, long b) { return (int)((a + b - 1) / b); };

    detect_kernel<<<1, 256, 0, stream>>>((const unsigned*)x, flag);

    // degrees (with self-loop)
    init_deg_kernel<<<cdiv(NN, 256), 256, 0, stream>>>(dinv, NN);
    count_deg_kernel<<<cdiv(NE, 256), 256, 0, stream>>>(edst, dinv, NE);
    rsqrt_kernel<<<cdiv(NN, 256), 256, 0, stream>>>(dinv, NN);

    // ---- GCN1 ----
    mm_kernel<IND, false, false><<<dim3(cdiv(NN, 16), 1), 256, 0, stream>>>(x, gcn1_w, bufA, NN, 64, flag);
    self_init_kernel<<<cdiv((long)NN * 64, 256), 256, 0, stream>>>(dinv, bufA, bufB, NN);
    gcn_edge_kernel<<<cdiv((long)NE * 64, 256), 256, 0, stream>>>(esrc, edst, dinv, bufA, bufB, NE);
    bias_bn_relu_kernel<<<cdiv((long)NN * 64, 256), 256, 0, stream>>>(bufB, gcn1_b, bn1_g, bn1_b, bn1_m, bn1_v, NN, flag);

    // ---- GAT1 (C=64) ----
    mm_kernel<64, true, true><<<dim3(cdiv(NN, 16), 8), 256, 0, stream>>>(bufB, gat1_w, htb, NN, 512, flag);
    att_scores_kernel<64><<<cdiv((long)NN * NH, 256), 256, 0, stream>>>(htb, gat1_as, gat1_ad, es, ed, NN, flag);
    init_mx_dn_kernel<<<cdiv((long)NN * NH, 256), 256, 0, stream>>>(mx, dn, NN * NH);
    att_edge_max_kernel<<<cdiv((long)NEP * NH, 256), 256, 0, stream>>>(esrc, edst, es, ed, elog, mx, NE, NEP);
    att_exp_sum_kernel<<<cdiv((long)NEP * NH, 256), 256, 0, stream>>>(edst, mx, dn, elog, NE, NEP);
    zero_kernel<<<cdiv((long)NN * 64, 256), 256, 0, stream>>>(bufA, NN * 64);
    att_message_kernel<64><<<cdiv(NEP, 4), 256, 0, stream>>>(esrc, edst, elog, dn, htb, bufA, NE, NEP);
    gat_bias_relu_kernel<<<cdiv((long)NN * 64, 256), 256, 0, stream>>>(bufA, gat1_b, NN, flag);

    // ---- GCN2 ----
    mm_kernel<64, true, false><<<dim3(cdiv(NN, 16), 1), 256, 0, stream>>>(bufA, gcn2_w, bufB, NN, 64, flag);
    self_init_kernel<<<cdiv((long)NN * 64, 256), 256, 0, stream>>>(dinv, bufB, bufA, NN);
    gcn_edge_kernel<<<cdiv((long)NE * 64, 256), 256, 0, stream>>>(esrc, edst, dinv, bufB, bufA, NE);
    bias_bn_relu_kernel<<<cdiv((long)NN * 64, 256), 256, 0, stream>>>(bufA, gcn2_b, bn2_g, bn2_b, bn2_m, bn2_v, NN, flag);

    // ---- GAT2 (C=32) ----
    mm_kernel<64, true, true><<<dim3(cdiv(NN, 16), 4), 256, 0, stream>>>(bufA, gat2_w, htb, NN, 256, flag);
    att_scores_kernel<32><<<cdiv((long)NN * NH, 256), 256, 0, stream>>>(htb, gat2_as, gat2_ad, es, ed, NN, flag);
    init_mx_dn_kernel<<<cdiv((long)NN * NH, 256), 256, 0, stream>>>(mx, dn, NN * NH);
    att_edge_max_kernel<<<cdiv((long)NEP * NH, 256), 256, 0, stream>>>(esrc, edst, es, ed, elog, mx, NE, NEP);
    att_exp_sum_kernel<<<cdiv((long)NEP * NH, 256), 256, 0, stream>>>(edst, mx, dn, elog, NE, NEP);
    zero_kernel<<<cdiv((long)NN * 32, 256), 256, 0, stream>>>(bufB, NN * 32);
    att_message_kernel<32><<<cdiv(NEP, 8), 256, 0, stream>>>(esrc, edst, elog, dn, htb, bufB, NE, NEP);

    // ---- log_softmax -> out ----
    logsoftmax_kernel<<<cdiv((long)NN * 32, 256), 256, 0, stream>>>(bufB, gat2_b, d_out, NN, flag);
}

// Round 6
// 1155.922 us; speedup vs baseline: 1.6723x; 1.6723x over previous
//
#include <hip/hip_runtime.h>
#include <hip/hip_bf16.h>

#define NN 50000
#define NE 800000
#define NEP (NE + NN)   // edges incl. self-loops
#define IND 128
#define NH 8

typedef __hip_bfloat16 bf16;
typedef __attribute__((ext_vector_type(8))) short short8;
typedef __attribute__((ext_vector_type(8))) __bf16 bf16x8;
typedef __attribute__((ext_vector_type(4))) float floatx4;

// float -> bf16 bits, round-to-nearest-even (finite inputs only)
static __device__ __forceinline__ short f2bf_bits(float f) {
    unsigned u = __float_as_uint(f);
    u = (u + 0x7fffu + ((u >> 16) & 1u)) >> 16;
    return (short)u;
}
// Order-preserving float<->uint encoding for atomicMax on floats
static __device__ __forceinline__ unsigned encf(float x) {
    unsigned u = __float_as_uint(x);
    return (u & 0x80000000u) ? ~u : (u | 0x80000000u);
}
static __device__ __forceinline__ float decf(unsigned u) {
    return __uint_as_float((u & 0x80000000u) ? (u & 0x7FFFFFFFu) : ~u);
}

// ---------------- utility kernels ----------------
__global__ void zero_kernel(float* p, int n) {
    int i = blockIdx.x * 256 + threadIdx.x;
    if (i < n) p[i] = 0.f;
}
__global__ void init_deg_kernel(float* deg, int n) {
    int i = blockIdx.x * 256 + threadIdx.x;
    if (i < n) deg[i] = 1.f;   // self-loop
}
__global__ void count_deg_kernel(const int* __restrict__ edst, float* deg, int e) {
    int i = blockIdx.x * 256 + threadIdx.x;
    if (i < e) atomicAdd(&deg[edst[i]], 1.f);
}
__global__ void rsqrt_kernel(float* deg, int n) {
    int i = blockIdx.x * 256 + threadIdx.x;
    if (i < n) deg[i] = rsqrtf(deg[i]);
}
__global__ void init_mx_dn_kernel(unsigned* mx, float* dn, int n) {
    int i = blockIdx.x * 256 + threadIdx.x;
    if (i < n) { mx[i] = encf(-1e30f); dn[i] = 0.f; }
}

// ---------------- MFMA matmul: C[n,M] = A[n,K] @ W[K,M], A/W fp32 in HBM ----------------
// Converted to bf16 (RNE) during LDS staging. Block 256 thr = 4 waves; tile 64x64.
// A-frag: A[m=lane&15][k=(lane>>4)*8+j]; B-frag: B[k=(lane>>4)*8+j][n=lane&15];
// C/D: col=lane&15, row=(lane>>4)*4+reg  (m89/m120-verified layouts).
template<int K, bool CBF16>
__global__ __launch_bounds__(256) void mm_mfma_kernel(const float* __restrict__ A,
        const float* __restrict__ W, void* __restrict__ C, int nrows, int M) {
    __shared__ __align__(16) short Alds[64][K + 8];   // +8 pad: rows stay 16B-aligned
    __shared__ __align__(16) short Wlds[64][K + 8];   // TRANSPOSED: Wlds[m][k]
    const int row0 = blockIdx.x * 64;
    const int m0   = blockIdx.y * 64;
    const int tid  = threadIdx.x;

    constexpr int KB = K / 8;
    for (int i = tid; i < 64 * KB; i += 256) {
        int r = i / KB, kb = i % KB;
        int row = row0 + r;
        short8 v = {0, 0, 0, 0, 0, 0, 0, 0};
        if (row < nrows) {
            const float* ap = A + (long)row * K + kb * 8;
            floatx4 va = *(const floatx4*)ap;
            floatx4 vb = *(const floatx4*)(ap + 4);
#pragma unroll
            for (int j = 0; j < 4; ++j) { v[j] = f2bf_bits(va[j]); v[4 + j] = f2bf_bits(vb[j]); }
        }
        *(short8*)&Alds[r][kb * 8] = v;
    }
    for (int i = tid; i < K * 64; i += 256) {
        int k = i >> 6, m = i & 63;
        Wlds[m][k] = f2bf_bits(W[(long)k * M + m0 + m]);
    }
    __syncthreads();

    const int lane = tid & 63, wave = tid >> 6;
    const int lr = lane & 15, q = lane >> 4;
    const int rw = wave * 16;
    floatx4 acc[4] = {};
#pragma unroll
    for (int k0 = 0; k0 < K; k0 += 32) {
        bf16x8 a = __builtin_bit_cast(bf16x8, *(const short8*)&Alds[rw + lr][k0 + q * 8]);
#pragma unroll
        for (int c = 0; c < 4; ++c) {
            bf16x8 b = __builtin_bit_cast(bf16x8, *(const short8*)&Wlds[c * 16 + lr][k0 + q * 8]);
            acc[c] = __builtin_amdgcn_mfma_f32_16x16x32_bf16(a, b, acc[c], 0, 0, 0);
        }
    }
#pragma unroll
    for (int c = 0; c < 4; ++c)
#pragma unroll
        for (int r = 0; r < 4; ++r) {
            int row = row0 + rw + q * 4 + r;
            if (row < nrows) {
                long o = (long)row * M + m0 + c * 16 + lr;
                if (CBF16) ((bf16*)C)[o] = __float2bfloat16(acc[c][r]);
                else       ((float*)C)[o] = acc[c][r];
            }
        }
}

// ---------------- GCN ----------------
__global__ void self_init_kernel(const float* __restrict__ dinv,
        const float* __restrict__ hin, float* __restrict__ hout, int n) {
    int idx = blockIdx.x * 256 + threadIdx.x;
    if (idx >= n * 64) return;
    float di = dinv[idx >> 6];
    hout[idx] = di * di * hin[idx];
}
__global__ void gcn_edge_kernel(const int* __restrict__ esrc, const int* __restrict__ edst,
        const float* __restrict__ dinv, const float* __restrict__ hin,
        float* __restrict__ hout, int e) {
    int idx = blockIdx.x * 256 + threadIdx.x;
    if (idx >= e * 64) return;
    int eid = idx >> 6, c = idx & 63;
    int s = esrc[eid], d = edst[eid];
    float coef = dinv[s] * dinv[d];
    atomicAdd(&hout[(long)d * 64 + c], coef * hin[(long)s * 64 + c]);
}
__global__ void bias_bn_relu_kernel(float* __restrict__ h, const float* b,
        const float* gamma, const float* beta, const float* mean, const float* var, int n) {
    int idx = blockIdx.x * 256 + threadIdx.x;
    if (idx >= n * 64) return;
    int c = idx & 63;
    float x = h[idx] + b[c];
    x = (x - mean[c]) * rsqrtf(var[c] + 1e-5f) * gamma[c] + beta[c];
    h[idx] = fmaxf(x, 0.f);
}

// ---------------- GAT ----------------
template<int C>
__global__ void att_scores_kernel(const bf16* __restrict__ ht,
        const float* __restrict__ asrc, const float* __restrict__ adst,
        float* __restrict__ es, float* __restrict__ ed, int n) {
    int idx = blockIdx.x * 256 + threadIdx.x;
    if (idx >= n * NH) return;
    int nd = idx >> 3, h = idx & 7;
    const bf16* hp = ht + (long)nd * NH * C + h * C;
    float s = 0.f, d = 0.f;
    for (int c = 0; c < C; ++c) {
        float v = __bfloat162float(hp[c]);
        s += v * asrc[h * C + c];
        d += v * adst[h * C + c];
    }
    es[idx] = s; ed[idx] = d;
}
__global__ void att_edge_max_kernel(const int* __restrict__ esrc, const int* __restrict__ edst,
        const float* __restrict__ es, const float* __restrict__ ed,
        float* __restrict__ elog, unsigned* __restrict__ mx, int e, int ep) {
    int idx = blockIdx.x * 256 + threadIdx.x;
    if (idx >= ep * NH) return;
    int eid = idx >> 3, h = idx & 7;
    int s, d;
    if (eid < e) { s = esrc[eid]; d = edst[eid]; } else { s = d = eid - e; }
    float v = es[s * NH + h] + ed[d * NH + h];
    v = v > 0.f ? v : 0.2f * v;   // leaky_relu 0.2
    elog[idx] = v;
    atomicMax(&mx[d * NH + h], encf(v));
}
__global__ void att_exp_sum_kernel(const int* __restrict__ edst,
        const unsigned* __restrict__ mx, float* __restrict__ dn,
        float* __restrict__ elog, int e, int ep) {
    int idx = blockIdx.x * 256 + threadIdx.x;
    if (idx >= ep * NH) return;
    int eid = idx >> 3, h = idx & 7;
    int d = (eid < e) ? edst[eid] : eid - e;
    float m = decf(mx[d * NH + h]);
    float ex = expf(fminf(elog[idx] - m, 0.f));
    elog[idx] = ex;
    atomicAdd(&dn[d * NH + h], ex);
}
template<int C>
__global__ __launch_bounds__(256) void att_message_kernel(const int* __restrict__ esrc,
        const int* __restrict__ edst, const float* __restrict__ ex,
        const float* __restrict__ dn, const bf16* __restrict__ ht,
        float* __restrict__ out, int e, int ep) {
    constexpr int EPB = 256 / C;
    __shared__ float alpha[EPB][NH];
    __shared__ int ssrc[EPB], sdst[EPB];
    const int e0 = blockIdx.x * EPB;
    const int tid = threadIdx.x;
    if (tid < EPB * NH) {
        int le = tid >> 3, h = tid & 7;
        int eid = e0 + le;
        if (eid < ep) {
            int s, d;
            if (eid < e) { s = esrc[eid]; d = edst[eid]; } else { s = d = eid - e; }
            if (h == 0) { ssrc[le] = s; sdst[le] = d; }
            alpha[le][h] = ex[(long)eid * NH + h] / (dn[d * NH + h] + 1e-16f);
        }
    }
    __syncthreads();
    int le = tid / C, c = tid % C;
    int eid = e0 + le;
    if (eid >= ep) return;
    int s = ssrc[le], d = sdst[le];
    const bf16* hp = ht + (long)s * NH * C + c;
    float acc = 0.f;
#pragma unroll
    for (int h = 0; h < NH; ++h) acc += alpha[le][h] * __bfloat162float(hp[h * C]);
    atomicAdd(&out[(long)d * C + c], acc);
}
__global__ void gat_bias_relu_kernel(float* __restrict__ h, const float* b, int n) {
    int idx = blockIdx.x * 256 + threadIdx.x;
    if (idx >= n * 64) return;
    float v = h[idx] * 0.125f + b[idx & 63];
    h[idx] = fmaxf(v, 0.f);
}
__global__ __launch_bounds__(256) void logsoftmax_kernel(const float* __restrict__ acc,
        const float* __restrict__ b, float* __restrict__ out, int n) {
    int idx = blockIdx.x * 256 + threadIdx.x;
    int nd = idx >> 5, lane = idx & 31;
    if (nd >= n) return;
    float v = acc[idx] * 0.125f + b[lane];
    float m = v;
    for (int off = 16; off; off >>= 1) m = fmaxf(m, __shfl_xor(m, off, 32));
    float exv = expf(v - m);
    float ssum = exv;
    for (int off = 16; off; off >>= 1) ssum += __shfl_xor(ssum, off, 32);
    out[idx] = v - m - logf(ssum);
}

// ---------------- launch ----------------
extern "C" void kernel_launch(void* const* d_in, const int* in_sizes, int n_in,
                              void* d_out, int out_size, void* d_ws, size_t ws_size,
                              hipStream_t stream) {
    // All float tensors are fp32 (reference dtypes); verified: round-1 build's runtime
    // dtype dispatch passed on the fp32 path, hard-coded-bf16 builds all NaN'd.
    const float* x        = (const float*)d_in[0];
    const int*   eidx     = (const int*)d_in[1];
    const float* gcn1_w   = (const float*)d_in[2];
    const float* gcn1_b   = (const float*)d_in[3];
    const float* bn1_g    = (const float*)d_in[4];
    const float* bn1_b    = (const float*)d_in[5];
    const float* bn1_m    = (const float*)d_in[6];
    const float* bn1_v    = (const float*)d_in[7];
    const float* gat1_w   = (const float*)d_in[8];
    const float* gat1_as  = (const float*)d_in[9];
    const float* gat1_ad  = (const float*)d_in[10];
    const float* gat1_b   = (const float*)d_in[11];
    const float* gcn2_w   = (const float*)d_in[12];
    const float* gcn2_b   = (const float*)d_in[13];
    const float* bn2_g    = (const float*)d_in[14];
    const float* bn2_b    = (const float*)d_in[15];
    const float* bn2_m    = (const float*)d_in[16];
    const float* bn2_v    = (const float*)d_in[17];
    const float* gat2_w   = (const float*)d_in[18];
    const float* gat2_as  = (const float*)d_in[19];
    const float* gat2_ad  = (const float*)d_in[20];
    const float* gat2_b   = (const float*)d_in[21];
    float* out = (float*)d_out;

    const int* esrc = eidx;
    const int* edst = eidx + NE;

    // EXACT round-1(B) workspace layout (proven safe: ~110.6 MB)
    float* ws = (float*)d_ws;
    float*    dinv = ws + 64;
    float*    bufA = dinv + 50048;                          // N*64 f32
    float*    bufB = bufA + (size_t)NN * 64;                // N*64 f32
    float*    es   = bufB + (size_t)NN * 64;                // N*8 f32
    float*    ed   = es + (size_t)NN * NH;                  // N*8 f32
    unsigned* mx   = (unsigned*)(ed + (size_t)NN * NH);     // N*8 u32
    float*    dn   = ed + (size_t)NN * NH * 2;              // N*8 f32
    float*    elog = dn + (size_t)NN * NH;                  // NEP*8 f32
    bf16*     htb  = (bf16*)(elog + (size_t)NEP * NH);      // N*512 bf16

    auto cdiv = [](long a, long b) { return (int)((a + b - 1) / b); };
    const int GB = cdiv(NN, 64);   // 782 row-blocks

    // degrees (with self-loop)
    init_deg_kernel<<<cdiv(NN, 256), 256, 0, stream>>>(dinv, NN);
    count_deg_kernel<<<cdiv(NE, 256), 256, 0, stream>>>(edst, dinv, NE);
    rsqrt_kernel<<<cdiv(NN, 256), 256, 0, stream>>>(dinv, NN);

    // ---- GCN1 ----
    mm_mfma_kernel<IND, false><<<dim3(GB, 1), 256, 0, stream>>>(x, gcn1_w, bufA, NN, 64);
    self_init_kernel<<<cdiv((long)NN * 64, 256), 256, 0, stream>>>(dinv, bufA, bufB, NN);
    gcn_edge_kernel<<<cdiv((long)NE * 64, 256), 256, 0, stream>>>(esrc, edst, dinv, bufA, bufB, NE);
    bias_bn_relu_kernel<<<cdiv((long)NN * 64, 256), 256, 0, stream>>>(bufB, gcn1_b, bn1_g, bn1_b, bn1_m, bn1_v, NN);

    // ---- GAT1 (C=64) ----
    mm_mfma_kernel<64, true><<<dim3(GB, 8), 256, 0, stream>>>(bufB, gat1_w, htb, NN, 512);
    att_scores_kernel<64><<<cdiv((long)NN * NH, 256), 256, 0, stream>>>(htb, gat1_as, gat1_ad, es, ed, NN);
    init_mx_dn_kernel<<<cdiv((long)NN * NH, 256), 256, 0, stream>>>(mx, dn, NN * NH);
    att_edge_max_kernel<<<cdiv((long)NEP * NH, 256), 256, 0, stream>>>(esrc, edst, es, ed, elog, mx, NE, NEP);
    att_exp_sum_kernel<<<cdiv((long)NEP * NH, 256), 256, 0, stream>>>(edst, mx, dn, elog, NE, NEP);
    zero_kernel<<<cdiv((long)NN * 64, 256), 256, 0, stream>>>(bufA, NN * 64);
    att_message_kernel<64><<<cdiv(NEP, 4), 256, 0, stream>>>(esrc, edst, elog, dn, htb, bufA, NE, NEP);
    gat_bias_relu_kernel<<<cdiv((long)NN * 64, 256), 256, 0, stream>>>(bufA, gat1_b, NN);

    // ---- GCN2 ----
    mm_mfma_kernel<64, false><<<dim3(GB, 1), 256, 0, stream>>>(bufA, gcn2_w, bufB, NN, 64);
    self_init_kernel<<<cdiv((long)NN * 64, 256), 256, 0, stream>>>(dinv, bufB, bufA, NN);
    gcn_edge_kernel<<<cdiv((long)NE * 64, 256), 256, 0, stream>>>(esrc, edst, dinv, bufB, bufA, NE);
    bias_bn_relu_kernel<<<cdiv((long)NN * 64, 256), 256, 0, stream>>>(bufA, gcn2_b, bn2_g, bn2_b, bn2_m, bn2_v, NN);

    // ---- GAT2 (C=32) ----
    mm_mfma_kernel<64, true><<<dim3(GB, 4), 256, 0, stream>>>(bufA, gat2_w, htb, NN, 256);
    att_scores_kernel<32><<<cdiv((long)NN * NH, 256), 256, 0, stream>>>(htb, gat2_as, gat2_ad, es, ed, NN);
    init_mx_dn_kernel<<<cdiv((long)NN * NH, 256), 256, 0, stream>>>(mx, dn, NN * NH);
    att_edge_max_kernel<<<cdiv((long)NEP * NH, 256), 256, 0, stream>>>(esrc, edst, es, ed, elog, mx, NE, NEP);
    att_exp_sum_kernel<<<cdiv((long)NEP * NH, 256), 256, 0, stream>>>(edst, mx, dn, elog, NE, NEP);
    zero_kernel<<<cdiv((long)NN * 32, 256), 256, 0, stream>>>(bufB, NN * 32);
    att_message_kernel<32><<<cdiv(NEP, 8), 256, 0, stream>>>(esrc, edst, elog, dn, htb, bufB, NE, NEP);

    // ---- log_softmax -> fp32 out ----
    logsoftmax_kernel<<<cdiv((long)NN * 32, 256), 256, 0, stream>>>(bufB, gat2_b, out, NN);
}

// Round 7
// 763.946 us; speedup vs baseline: 2.5303x; 1.5131x over previous
//
#include <hip/hip_runtime.h>
#include <hip/hip_bf16.h>

#define NN 50000
#define NE 800000
#define IND 128
#define NH 8

typedef __hip_bfloat16 bf16;
typedef __attribute__((ext_vector_type(8))) short short8;
typedef __attribute__((ext_vector_type(8))) __bf16 bf16x8;
typedef __attribute__((ext_vector_type(4))) float floatx4;

// float -> bf16 bits, round-to-nearest-even (finite inputs only)
static __device__ __forceinline__ short f2bf_bits(float f) {
    unsigned u = __float_as_uint(f);
    u = (u + 0x7fffu + ((u >> 16) & 1u)) >> 16;
    return (short)u;
}

// ---------------- CSR build ----------------
__global__ void zero_int_kernel(int* p, int n) {
    int i = blockIdx.x * 256 + threadIdx.x;
    if (i < n) p[i] = 0;
}
__global__ void hist_kernel(const int* __restrict__ edst, int* __restrict__ cnt, int e) {
    int i = blockIdx.x * 256 + threadIdx.x;
    if (i < e) atomicAdd(&cnt[edst[i]], 1);
}
// single block, 1024 threads: exclusive scan of cnt -> rowptr & cursor; dinv = rsqrt(deg+1)
__global__ __launch_bounds__(1024) void scan_kernel(const int* __restrict__ cnt,
        int* __restrict__ rowptr, int* __restrict__ cursor, float* __restrict__ dinv) {
    __shared__ int psum[1024];
    const int tid = threadIdx.x;
    const int per = (NN + 1023) / 1024;
    const int base = tid * per;
    int s = 0;
    for (int i = 0; i < per; ++i) {
        int idx = base + i;
        if (idx < NN) s += cnt[idx];
    }
    psum[tid] = s;
    __syncthreads();
    for (int off = 1; off < 1024; off <<= 1) {
        int v = 0;
        if (tid >= off) v = psum[tid - off];
        __syncthreads();
        if (tid >= off) psum[tid] += v;
        __syncthreads();
    }
    int run = psum[tid] - s;   // exclusive prefix of this chunk
    for (int i = 0; i < per; ++i) {
        int idx = base + i;
        if (idx < NN) {
            rowptr[idx] = run;
            cursor[idx] = run;
            int c = cnt[idx];
            dinv[idx] = rsqrtf((float)c + 1.f);
            run += c;
        }
    }
    if (tid == 0) rowptr[NN] = NE;
}
__global__ void scatter_kernel(const int* __restrict__ esrc, const int* __restrict__ edst,
        int* __restrict__ cursor, int* __restrict__ csrc, int e) {
    int i = blockIdx.x * 256 + threadIdx.x;
    if (i >= e) return;
    int d = edst[i];
    int pos = atomicAdd(&cursor[d], 1);
    csrc[pos] = esrc[i];
}

// ---------------- MFMA matmul: C[n,M] = A[n,K] @ W[K,M], A/W fp32 in HBM ----------------
// bf16 (RNE) conversion during LDS staging. 256 thr = 4 waves; tile 64x64.
// A-frag: A[m=lane&15][k=(lane>>4)*8+j]; B-frag: B[k=(lane>>4)*8+j][n=lane&15];
// C/D: col=lane&15, row=(lane>>4)*4+reg  (verified R6).
template<int K, bool CBF16>
__global__ __launch_bounds__(256) void mm_mfma_kernel(const float* __restrict__ A,
        const float* __restrict__ W, void* __restrict__ C, int nrows, int M) {
    __shared__ __align__(16) short Alds[64][K + 8];
    __shared__ __align__(16) short Wlds[64][K + 8];   // transposed: Wlds[m][k]
    const int row0 = blockIdx.x * 64;
    const int m0   = blockIdx.y * 64;
    const int tid  = threadIdx.x;

    constexpr int KB = K / 8;
    for (int i = tid; i < 64 * KB; i += 256) {
        int r = i / KB, kb = i % KB;
        int row = row0 + r;
        short8 v = {0, 0, 0, 0, 0, 0, 0, 0};
        if (row < nrows) {
            const float* ap = A + (long)row * K + kb * 8;
            floatx4 va = *(const floatx4*)ap;
            floatx4 vb = *(const floatx4*)(ap + 4);
#pragma unroll
            for (int j = 0; j < 4; ++j) { v[j] = f2bf_bits(va[j]); v[4 + j] = f2bf_bits(vb[j]); }
        }
        *(short8*)&Alds[r][kb * 8] = v;
    }
    for (int i = tid; i < K * 64; i += 256) {
        int k = i >> 6, m = i & 63;
        Wlds[m][k] = f2bf_bits(W[(long)k * M + m0 + m]);
    }
    __syncthreads();

    const int lane = tid & 63, wave = tid >> 6;
    const int lr = lane & 15, q = lane >> 4;
    const int rw = wave * 16;
    floatx4 acc[4] = {};
#pragma unroll
    for (int k0 = 0; k0 < K; k0 += 32) {
        bf16x8 a = __builtin_bit_cast(bf16x8, *(const short8*)&Alds[rw + lr][k0 + q * 8]);
#pragma unroll
        for (int c = 0; c < 4; ++c) {
            bf16x8 b = __builtin_bit_cast(bf16x8, *(const short8*)&Wlds[c * 16 + lr][k0 + q * 8]);
            acc[c] = __builtin_amdgcn_mfma_f32_16x16x32_bf16(a, b, acc[c], 0, 0, 0);
        }
    }
#pragma unroll
    for (int c = 0; c < 4; ++c)
#pragma unroll
        for (int r = 0; r < 4; ++r) {
            int row = row0 + rw + q * 4 + r;
            if (row < nrows) {
                long o = (long)row * M + m0 + c * 16 + lr;
                if (CBF16) ((bf16*)C)[o] = __float2bfloat16(acc[c][r]);
                else       ((float*)C)[o] = acc[c][r];
            }
        }
}

// ---------------- fused GCN aggregate + bias + BN + ReLU (CSR, no atomics) ----------------
// one wave per dst node; lane = channel (64). hin bf16.
__global__ __launch_bounds__(256) void gcn_fused_kernel(const int* __restrict__ rowptr,
        const int* __restrict__ csrc, const float* __restrict__ dinv,
        const bf16* __restrict__ hin, const float* __restrict__ b,
        const float* __restrict__ gamma, const float* __restrict__ beta,
        const float* __restrict__ mean, const float* __restrict__ var,
        float* __restrict__ actout) {
    const int node = blockIdx.x * 4 + (threadIdx.x >> 6);
    if (node >= NN) return;
    const int lane = threadIdx.x & 63;
    const int beg = rowptr[node], end = rowptr[node + 1];
    const float di = dinv[node];
    float acc = di * __bfloat162float(hin[(long)node * 64 + lane]);   // self
    int ei = beg;
    for (; ei + 4 <= end; ei += 4) {
        int s0 = csrc[ei], s1 = csrc[ei + 1], s2 = csrc[ei + 2], s3 = csrc[ei + 3];
        float w0 = dinv[s0], w1 = dinv[s1], w2 = dinv[s2], w3 = dinv[s3];
        float h0 = __bfloat162float(hin[(long)s0 * 64 + lane]);
        float h1 = __bfloat162float(hin[(long)s1 * 64 + lane]);
        float h2 = __bfloat162float(hin[(long)s2 * 64 + lane]);
        float h3 = __bfloat162float(hin[(long)s3 * 64 + lane]);
        acc += w0 * h0 + w1 * h1 + w2 * h2 + w3 * h3;
    }
    for (; ei < end; ++ei) {
        int s = csrc[ei];
        acc += dinv[s] * __bfloat162float(hin[(long)s * 64 + lane]);
    }
    float x = acc * di + b[lane];
    x = (x - mean[lane]) * rsqrtf(var[lane] + 1e-5f) * gamma[lane] + beta[lane];
    actout[(long)node * 64 + lane] = fmaxf(x, 0.f);
}

// ---------------- per-node attention scores ----------------
template<int C>
__global__ void att_scores_kernel(const bf16* __restrict__ ht,
        const float* __restrict__ asrc, const float* __restrict__ adst,
        float* __restrict__ es, float* __restrict__ ed, int n) {
    int idx = blockIdx.x * 256 + threadIdx.x;
    if (idx >= n * NH) return;
    int nd = idx >> 3, h = idx & 7;
    const bf16* hp = ht + (long)nd * NH * C + h * C;
    float s = 0.f, d = 0.f;
    for (int c = 0; c < C; ++c) {
        float v = __bfloat162float(hp[c]);
        s += v * asrc[h * C + c];
        d += v * adst[h * C + c];
    }
    es[idx] = s; ed[idx] = d;
}

// ---------------- fused GAT (CSR): online softmax + message, no atomics ----------------
// one wave per dst node. Phase A: lanes = (slot=lane>>3, h=lane&7) online-softmax 8 edges/iter,
// butterfly-combine over slots. Phase B: recompute alpha, __shfl-broadcast, gather ht.
// LSM: fuse log_softmax epilogue (GAT2), else ReLU(acc/8 + bias) (GAT1).
template<int C, bool LSM>
__global__ __launch_bounds__(256) void gat_fused_kernel(const int* __restrict__ rowptr,
        const int* __restrict__ csrc, const float* __restrict__ es, const float* __restrict__ ed,
        const bf16* __restrict__ ht, const float* __restrict__ bias, float* __restrict__ outp) {
    const int node = blockIdx.x * 4 + (threadIdx.x >> 6);
    if (node >= NN) return;
    const int lane = threadIdx.x & 63;
    const int h = lane & 7, slot = lane >> 3;
    const int beg = rowptr[node], end = rowptr[node + 1];
    const float edr = ed[node * NH + h];

    // self-edge logit (per lane's head)
    float selfe = es[node * NH + h] + edr;
    selfe = selfe > 0.f ? selfe : 0.2f * selfe;

    // ---- Phase A: online softmax (m, den) ----
    float m, den;
    if (slot == 0) { m = selfe; den = 1.f; }
    else           { m = -3e38f; den = 0.f; }
    for (int base = beg; base < end; base += 8) {
        int ei = base + slot;
        float e = -3e38f;
        if (ei < end) {
            int s = csrc[ei];
            e = es[s * NH + h] + edr;
            e = e > 0.f ? e : 0.2f * e;
        }
        float mn = fmaxf(m, e);
        den = den * __expf(m - mn) + ((ei < end) ? __expf(e - mn) : 0.f);
        m = mn;
    }
#pragma unroll
    for (int off = 8; off < 64; off <<= 1) {
        float m2 = __shfl_xor(m, off), d2 = __shfl_xor(den, off);
        float mn = fmaxf(m, m2);
        den = den * __expf(m - mn) + d2 * __expf(m2 - mn);
        m = mn;
    }
    const float invden = 1.f / (den + 1e-16f);

    // ---- Phase B: alpha-weighted gather-accumulate ----
    float acc = 0.f;
    if (C == 64) {
        const int c = lane;
        for (int base = beg; base < end; base += 8) {
            int ei = base + slot;
            float al = 0.f; int sl = 0;
            if (ei < end) {
                sl = csrc[ei];
                float e = es[sl * NH + h] + edr;
                e = e > 0.f ? e : 0.2f * e;
                al = __expf(e - m) * invden;
            }
            int ecnt = end - base; if (ecnt > 8) ecnt = 8;
#pragma unroll
            for (int j = 0; j < 8; ++j) {
                if (j >= ecnt) break;
                int s = __shfl(sl, j * 8);
                const bf16* hp = ht + (long)s * (NH * 64) + c;
#pragma unroll
                for (int hh = 0; hh < 8; ++hh)
                    acc += __shfl(al, j * 8 + hh) * __bfloat162float(hp[hh * 64]);
            }
        }
        {   // self
            float aself = __expf(selfe - m) * invden;
            const bf16* hp = ht + (long)node * (NH * 64) + c;
#pragma unroll
            for (int hh = 0; hh < 8; ++hh)
                acc += __shfl(aself, hh) * __bfloat162float(hp[hh * 64]);
        }
        float v = acc * 0.125f + bias[c];
        outp[(long)node * 64 + c] = fmaxf(v, 0.f);
    } else {   // C == 32: halves process alternating edges, combine at end
        const int c = lane & 31, half = lane >> 5;
        for (int base = beg; base < end; base += 8) {
            int ei = base + slot;
            float al = 0.f; int sl = 0;
            if (ei < end) {
                sl = csrc[ei];
                float e = es[sl * NH + h] + edr;
                e = e > 0.f ? e : 0.2f * e;
                al = __expf(e - m) * invden;
            }
            int ecnt = end - base; if (ecnt > 8) ecnt = 8;
#pragma unroll
            for (int jj = 0; jj < 4; ++jj) {
                int j = jj * 2 + half;
                if (j < ecnt) {
                    int s = __shfl(sl, j * 8);
                    const bf16* hp = ht + (long)s * (NH * 32) + c;
#pragma unroll
                    for (int hh = 0; hh < 8; ++hh)
                        acc += __shfl(al, j * 8 + hh) * __bfloat162float(hp[hh * 32]);
                }
            }
        }
        {   // self: halves split heads
            float aself = __expf(selfe - m) * invden;
            const bf16* hp = ht + (long)node * (NH * 32) + c;
#pragma unroll
            for (int hh = 0; hh < 4; ++hh) {
                int h2 = half * 4 + hh;
                acc += __shfl(aself, h2) * __bfloat162float(hp[h2 * 32]);
            }
        }
        acc += __shfl_xor(acc, 32);
        float v = acc * 0.125f + bias[c];
        if (LSM) {
            float mv = v;
#pragma unroll
            for (int off = 16; off; off >>= 1) mv = fmaxf(mv, __shfl_xor(mv, off, 32));
            float ex = __expf(v - mv), sm = ex;
#pragma unroll
            for (int off = 16; off; off >>= 1) sm += __shfl_xor(sm, off, 32);
            if (half == 0) outp[(long)node * 32 + c] = v - mv - logf(sm);
        } else {
            if (half == 0) outp[(long)node * 32 + c] = fmaxf(v, 0.f);
        }
    }
}

// ---------------- launch ----------------
extern "C" void kernel_launch(void* const* d_in, const int* in_sizes, int n_in,
                              void* d_out, int out_size, void* d_ws, size_t ws_size,
                              hipStream_t stream) {
    const float* x        = (const float*)d_in[0];
    const int*   eidx     = (const int*)d_in[1];
    const float* gcn1_w   = (const float*)d_in[2];
    const float* gcn1_b   = (const float*)d_in[3];
    const float* bn1_g    = (const float*)d_in[4];
    const float* bn1_b    = (const float*)d_in[5];
    const float* bn1_m    = (const float*)d_in[6];
    const float* bn1_v    = (const float*)d_in[7];
    const float* gat1_w   = (const float*)d_in[8];
    const float* gat1_as  = (const float*)d_in[9];
    const float* gat1_ad  = (const float*)d_in[10];
    const float* gat1_b   = (const float*)d_in[11];
    const float* gcn2_w   = (const float*)d_in[12];
    const float* gcn2_b   = (const float*)d_in[13];
    const float* bn2_g    = (const float*)d_in[14];
    const float* bn2_b    = (const float*)d_in[15];
    const float* bn2_m    = (const float*)d_in[16];
    const float* bn2_v    = (const float*)d_in[17];
    const float* gat2_w   = (const float*)d_in[18];
    const float* gat2_as  = (const float*)d_in[19];
    const float* gat2_ad  = (const float*)d_in[20];
    const float* gat2_b   = (const float*)d_in[21];
    float* out = (float*)d_out;

    const int* esrc = eidx;
    const int* edst = eidx + NE;

    // workspace (all offsets 64-element padded; ~78 MB, < proven-safe 110.6 MB)
    float* ws = (float*)d_ws;
    int*   cnt    = (int*)ws;                     // 50048
    int*   rowptr = cnt + 50048;                  // 50048 (uses NN+1)
    int*   cursor = rowptr + 50048;               // 50048
    int*   csrc   = cursor + 50048;               // 800000
    float* dinv   = (float*)(csrc + 800000);      // 50048
    float* es     = dinv + 50048;                 // 400000
    float* ed     = es + 400000;                  // 400000
    float* act    = ed + 400000;                  // N*64 f32 (16B-aligned)
    bf16*  mmbf   = (bf16*)(act + (size_t)NN * 64);   // N*64 bf16
    bf16*  htb    = mmbf + (size_t)NN * 64;           // N*512 bf16

    auto cdiv = [](long a, long b) { return (int)((a + b - 1) / b); };
    const int GB = cdiv(NN, 64);       // 782 row-blocks for matmuls
    const int NB = cdiv(NN, 4);        // 12500 node-blocks (wave per node)

    // ---- CSR build (reused by all 4 aggregations) ----
    zero_int_kernel<<<cdiv(NN, 256), 256, 0, stream>>>(cnt, NN);
    hist_kernel<<<cdiv(NE, 256), 256, 0, stream>>>(edst, cnt, NE);
    scan_kernel<<<1, 1024, 0, stream>>>(cnt, rowptr, cursor, dinv);
    scatter_kernel<<<cdiv(NE, 256), 256, 0, stream>>>(esrc, edst, cursor, csrc, NE);

    // ---- GCN1 ----
    mm_mfma_kernel<IND, true><<<dim3(GB, 1), 256, 0, stream>>>(x, gcn1_w, mmbf, NN, 64);
    gcn_fused_kernel<<<NB, 256, 0, stream>>>(rowptr, csrc, dinv, mmbf,
        gcn1_b, bn1_g, bn1_b, bn1_m, bn1_v, act);

    // ---- GAT1 (C=64) ----
    mm_mfma_kernel<64, true><<<dim3(GB, 8), 256, 0, stream>>>(act, gat1_w, htb, NN, 512);
    att_scores_kernel<64><<<cdiv((long)NN * NH, 256), 256, 0, stream>>>(htb, gat1_as, gat1_ad, es, ed, NN);
    gat_fused_kernel<64, false><<<NB, 256, 0, stream>>>(rowptr, csrc, es, ed, htb, gat1_b, act);

    // ---- GCN2 ----
    mm_mfma_kernel<64, true><<<dim3(GB, 1), 256, 0, stream>>>(act, gcn2_w, mmbf, NN, 64);
    gcn_fused_kernel<<<NB, 256, 0, stream>>>(rowptr, csrc, dinv, mmbf,
        gcn2_b, bn2_g, bn2_b, bn2_m, bn2_v, act);

    // ---- GAT2 (C=32) + log_softmax fused ----
    mm_mfma_kernel<64, true><<<dim3(GB, 4), 256, 0, stream>>>(act, gat2_w, htb, NN, 256);
    att_scores_kernel<32><<<cdiv((long)NN * NH, 256), 256, 0, stream>>>(htb, gat2_as, gat2_ad, es, ed, NN);
    gat_fused_kernel<32, true><<<NB, 256, 0, stream>>>(rowptr, csrc, es, ed, htb, gat2_b, out);
}